// Round 3
// baseline (162.772 us; speedup 1.0000x reference)
//
#include <hip/hip_runtime.h>
#include <math.h>

#define Udim 13
#define Vdim 13
#define Hdim 128
#define Wdim 160
#define HW (Hdim * Wdim)          // 20480
#define UV (Udim * Vdim)          // 169
#define TRUNC 4
#define NPIX (8 * HW)             // 163840
#define NPL 85                    // lane-group 0: planes 0..84; group 1: 85..168 (+1 pad)

// Lane-pair split: lanes k and k^32 share one pixel, each holding ~85 of the
// 169 (u,v) values in registers -> single HBM read, pass 2 fully in-register.
// 1280 blocks x 256 thr; launch_bounds(256,3) => <=170 VGPR, 12 waves/CU.
__global__ __launch_bounds__(256, 3) void flow_regression_kernel(
    const float* __restrict__ x, float* __restrict__ out) {
    int t    = threadIdx.x;
    int lane = t & 63;
    int g    = lane >> 5;         // plane group: 0 -> [0,85), 1 -> [85,169)
    int p32  = lane & 31;
    int wave = t >> 6;
    int pixel = blockIdx.x * 128 + wave * 32 + p32;   // HW%128==0 -> b uniform per wave
    int b  = pixel / HW;
    int hw = pixel - b * HW;

    const float* base = x + (size_t)b * UV * HW + hw + (size_t)(g * NPL) * HW;

    // ---- Single pass over HBM: load my 85 planes into registers ----
    // Each load instr: lanes 0-31 one 128B line (plane i), lanes 32-63 another
    // (plane 85+i) -> 2 full transactions, fully coalesced, all independent.
    float vals[NPL];
    #pragma unroll
    for (int i = 0; i < NPL - 1; ++i) vals[i] = base[(size_t)i * HW];
    vals[NPL - 1] = (g == 0) ? base[(size_t)(NPL - 1) * HW] : -INFINITY;  // pad g=1

    // ---- Local argmax (strict > => first index on ties) ----
    float m = vals[0];
    int mi = 0;
    #pragma unroll
    for (int i = 1; i < NPL; ++i)
        if (vals[i] > m) { m = vals[i]; mi = i; }
    mi += g * NPL;                // global plane index

    // ---- Combine across the lane pair; tie-break = smaller plane index ----
    float om = __shfl_xor(m, 32);
    int   oi = __shfl_xor(mi, 32);
    if (om > m || (om == m && oi < mi)) { m = om; mi = oi; }

    int ui = (mi * 158) >> 11;    // == mi/13 for mi in [0,169)
    int vi = mi - ui * Vdim;

    // ---- Pass 2: masked exp sums, entirely from registers ----
    float s = 0.f, su = 0.f, sv = 0.f;
    int u = g ? 6 : 0, v = g ? 7 : 0;   // (g*85)/13, (g*85)%13
    #pragma unroll
    for (int i = 0; i < NPL; ++i) {
        bool in = (u - ui <= TRUNC) && (ui - u <= TRUNC) &&
                  (v - vi <= TRUNC) && (vi - v <= TRUNC);
        float e = in ? __expf(vals[i] - m) : 0.f;  // pad val=-inf -> e=0 either way
        s  += e;
        su += e * (float)(u - 6);
        sv += e * (float)(v - 6);
        if (++v == Vdim) { v = 0; ++u; }
    }
    s  += __shfl_xor(s, 32);
    su += __shfl_xor(su, 32);
    sv += __shfl_xor(sv, 32);

    // ---- One lane of the pair writes (lanes 0-31: coalesced 128B stores) ----
    if (g == 0) {
        float inv = 1.0f / s;
        float* ob = out + (size_t)b * 2 * HW + hw;
        ob[0]  = su * inv;   // flowU
        ob[HW] = sv * inv;   // flowV
    }
}

extern "C" void kernel_launch(void* const* d_in, const int* in_sizes, int n_in,
                              void* d_out, int out_size, void* d_ws, size_t ws_size,
                              hipStream_t stream) {
    const float* x = (const float*)d_in[0];
    float* out = (float*)d_out;
    flow_regression_kernel<<<NPIX / 128, 256, 0, stream>>>(x, out);
}